// Round 1
// baseline (3736.141 us; speedup 1.0000x reference)
//
#include <hip/hip_runtime.h>
#include <stdint.h>

// ============================================================================
// LSTM (B=2048,T=256,D=32,H=256) + FC(256) on gfx950.
// Design R1: 64 persistent blocks x 512 threads. Block owns 32 batch rows x
// all 1024 gate cols. Per step: bf16 MFMA GEMM [32 x 1024 x K=288] with
// A=[h|x_t] staged in LDS, weights streamed from L2 in fragment-packed order.
// Gate cols interleaved mod-8 across waves so each wave owns i,f,g,o for its
// 32 hidden units -> c stays in VGPRs for all 256 steps. FC epilogue fused.
// MFMA layouts (learn_hip verified): A[m=lane&15][k=(lane>>4)*8+j],
// B^T same pattern, C/D: col=lane&15, row=(lane>>4)*4+reg.
// ============================================================================

typedef __attribute__((ext_vector_type(8))) short short8;
typedef __attribute__((ext_vector_type(4))) float f32x4;

#define LDSTRIDE 296  // 288 K-cols padded to break LDS bank strides

__device__ __forceinline__ short f2bf(float f) {
  uint32_t u = __builtin_bit_cast(uint32_t, f);
  u = (u + 0x7FFFu + ((u >> 16) & 1u)) >> 16;  // RNE
  return (short)(uint16_t)u;
}

__device__ __forceinline__ float sigmoidf_(float x) {
  return 1.0f / (1.0f + __expf(-x));
}
__device__ __forceinline__ float tanhf_(float x) {
  // exact at extremes: exp->inf gives 1, exp->0 gives -1
  return 1.0f - 2.0f / (__expf(2.0f * x) + 1.0f);
}

// ---------------------------------------------------------------------------
// Pack W_hh[1024x256] (K 0..255) and W_ih[1024x32] (K 256..287) into bf16
// fragment-major: frag (kt in 0..8, ct in 0..63), element (lane, j):
//   n = ct*16 + (lane&15), k = kt*32 + (lane>>4)*8 + j
// so a wave's B-frag load is one coalesced 1KB global_load_dwordx4.
// ---------------------------------------------------------------------------
__global__ void pack_w(const float* __restrict__ Whh, const float* __restrict__ Wih,
                       short* __restrict__ wpack) {
  int tid = blockIdx.x * 256 + threadIdx.x;  // 9*64*64 = 36864 threads
  if (tid >= 9 * 64 * 64) return;
  int lane = tid & 63;
  int frag = tid >> 6;        // kt*64 + ct
  int ct = frag & 63, kt = frag >> 6;
  int n = ct * 16 + (lane & 15);
  int k0 = kt * 32 + (lane >> 4) * 8;
  short8 v;
#pragma unroll
  for (int j = 0; j < 8; ++j) {
    int k = k0 + j;
    float f = (k < 256) ? Whh[n * 256 + k] : Wih[n * 32 + (k - 256)];
    v[j] = f2bf(f);
  }
  *(short8*)(wpack + (size_t)frag * 512 + lane * 8) = v;
}

// W_fc[256x256] -> frags (kt in 0..7, ct in 0..15), same element mapping.
__global__ void pack_wfc(const float* __restrict__ Wfc, short* __restrict__ wfc) {
  int tid = blockIdx.x * 256 + threadIdx.x;  // 8*16*64 = 8192 threads
  if (tid >= 8 * 16 * 64) return;
  int lane = tid & 63;
  int frag = tid >> 6;        // kt*16 + ct
  int ct = frag & 15, kt = frag >> 4;
  int n = ct * 16 + (lane & 15);
  int k0 = kt * 32 + (lane >> 4) * 8;
  short8 v;
#pragma unroll
  for (int j = 0; j < 8; ++j) v[j] = f2bf(Wfc[n * 256 + k0 + j]);
  *(short8*)(wfc + (size_t)frag * 512 + lane * 8) = v;
}

// ---------------------------------------------------------------------------
// Main persistent LSTM kernel. grid=64 (tileB=32), block=512 (8 waves).
// Wave w owns col-tiles ct = w + 8q, q=0..7: q = g*2 + ui, gate g, hidden
// group u = w + 8*ui -> each wave has all 4 gates for hidden units
// {u*16..u*16+15 : u in {w, w+8}}. c[r][ui][reg] lives in VGPRs.
// ---------------------------------------------------------------------------
__global__ __launch_bounds__(512, 2) void lstm_main(
    const float* __restrict__ obs, const short8* __restrict__ wpack,
    const short8* __restrict__ wfc, const float* __restrict__ b_ih,
    const float* __restrict__ b_hh, const float* __restrict__ b_fc,
    float* __restrict__ out) {
  __shared__ __align__(16) short A[32 * LDSTRIDE];  // [row][K=288 padded] bf16
  const int tid = threadIdx.x;
  const int w = tid >> 6;        // wave 0..7
  const int lane = tid & 63;
  const int l15 = lane & 15, quad = lane >> 4;
  const int row0 = blockIdx.x * 32;

  // h_0 = 0 (zero whole LDS buffer)
  for (int i = tid; i < 32 * LDSTRIDE; i += 512) A[i] = 0;

  // fused gate bias b_ih + b_hh for this lane's 8 (gate, ugroup) columns
  float bias[8];
#pragma unroll
  for (int g = 0; g < 4; ++g)
#pragma unroll
    for (int ui = 0; ui < 2; ++ui) {
      int idx = g * 256 + (w + ui * 8) * 16 + l15;
      bias[g * 2 + ui] = b_ih[idx] + b_hh[idx];
    }

  // stage x_0 (32 rows x 32 d, fp32 -> bf16)
  {
    int r = tid >> 4, dp = (tid & 15) * 2;
    const float2 x2 = *(const float2*)(obs + ((size_t)(row0 + r) * 256 + 0) * 32 + dp);
    A[r * LDSTRIDE + 256 + dp]     = f2bf(x2.x);
    A[r * LDSTRIDE + 256 + dp + 1] = f2bf(x2.y);
  }

  float c[16];  // c[r*8 + ui*4 + reg]
#pragma unroll
  for (int i = 0; i < 16; ++i) c[i] = 0.f;

  __syncthreads();

  for (int t = 0; t < 256; ++t) {
    f32x4 acc[2][8];
#pragma unroll
    for (int r = 0; r < 2; ++r)
#pragma unroll
      for (int q = 0; q < 8; ++q) acc[r][q] = (f32x4){0.f, 0.f, 0.f, 0.f};

    // GEMM: z[32 x 1024] = [h | x_t] @ [W_hh | W_ih]^T, K = 288 = 9 * 32
#pragma unroll
    for (int kt = 0; kt < 9; ++kt) {
      short8 a0 = *(const short8*)&A[l15 * LDSTRIDE + kt * 32 + quad * 8];
      short8 a1 = *(const short8*)&A[(16 + l15) * LDSTRIDE + kt * 32 + quad * 8];
#pragma unroll
      for (int q = 0; q < 8; ++q) {
        int ct = w + 8 * q;
        short8 b = wpack[(kt * 64 + ct) * 64 + lane];
        acc[0][q] = __builtin_amdgcn_mfma_f32_16x16x32_bf16(a0, b, acc[0][q], 0, 0, 0);
        acc[1][q] = __builtin_amdgcn_mfma_f32_16x16x32_bf16(a1, b, acc[1][q], 0, 0, 0);
      }
    }
    __syncthreads();  // all waves done READING A for step t

    // gate nonlinearities + state update; write h_{t+1} (bf16) back into A
#pragma unroll
    for (int r = 0; r < 2; ++r)
#pragma unroll
      for (int ui = 0; ui < 2; ++ui) {
        f32x4 zi = acc[r][0 + ui], zf = acc[r][2 + ui];
        f32x4 zg = acc[r][4 + ui], zo = acc[r][6 + ui];
#pragma unroll
        for (int reg = 0; reg < 4; ++reg) {
          float iv = sigmoidf_(zi[reg] + bias[0 + ui]);
          float fv = sigmoidf_(zf[reg] + bias[2 + ui]);
          float gv = tanhf_(zg[reg] + bias[4 + ui]);
          float ov = sigmoidf_(zo[reg] + bias[6 + ui]);
          float cc = fv * c[r * 8 + ui * 4 + reg] + iv * gv;
          c[r * 8 + ui * 4 + reg] = cc;
          float hv = ov * tanhf_(cc);
          int row = r * 16 + quad * 4 + reg;
          int col = (w + ui * 8) * 16 + l15;
          A[row * LDSTRIDE + col] = f2bf(hv);
        }
      }
    // stage x_{t+1}
    if (t < 255) {
      int r = tid >> 4, dp = (tid & 15) * 2;
      const float2 x2 =
          *(const float2*)(obs + ((size_t)(row0 + r) * 256 + (t + 1)) * 32 + dp);
      A[r * LDSTRIDE + 256 + dp]     = f2bf(x2.x);
      A[r * LDSTRIDE + 256 + dp + 1] = f2bf(x2.y);
    }
    __syncthreads();  // h_{t+1}/x_{t+1} visible before next K-loop
  }

  // FC epilogue: out[32 x 256] = h_last @ W_fc^T + b_fc, K = 256 = 8 * 32
  f32x4 ao[2][2];
#pragma unroll
  for (int r = 0; r < 2; ++r)
#pragma unroll
    for (int qi = 0; qi < 2; ++qi) ao[r][qi] = (f32x4){0.f, 0.f, 0.f, 0.f};
#pragma unroll
  for (int kt = 0; kt < 8; ++kt) {
    short8 a0 = *(const short8*)&A[l15 * LDSTRIDE + kt * 32 + quad * 8];
    short8 a1 = *(const short8*)&A[(16 + l15) * LDSTRIDE + kt * 32 + quad * 8];
#pragma unroll
    for (int qi = 0; qi < 2; ++qi) {
      int ct = w + 8 * qi;
      short8 b = wfc[(kt * 16 + ct) * 64 + lane];
      ao[0][qi] = __builtin_amdgcn_mfma_f32_16x16x32_bf16(a0, b, ao[0][qi], 0, 0, 0);
      ao[1][qi] = __builtin_amdgcn_mfma_f32_16x16x32_bf16(a1, b, ao[1][qi], 0, 0, 0);
    }
  }
#pragma unroll
  for (int qi = 0; qi < 2; ++qi) {
    float bv = b_fc[(w + qi * 8) * 16 + l15];
#pragma unroll
    for (int r = 0; r < 2; ++r)
#pragma unroll
      for (int reg = 0; reg < 4; ++reg) {
        int row = row0 + r * 16 + quad * 4 + reg;
        int col = (w + qi * 8) * 16 + l15;
        out[(size_t)row * 256 + col] = ao[r][qi][reg] + bv;
      }
  }
}

extern "C" void kernel_launch(void* const* d_in, const int* in_sizes, int n_in,
                              void* d_out, int out_size, void* d_ws, size_t ws_size,
                              hipStream_t stream) {
  const float* obs  = (const float*)d_in[0];   // [2048,256,32]
  const float* W_ih = (const float*)d_in[1];   // [1024,32]
  const float* W_hh = (const float*)d_in[2];   // [1024,256]
  const float* b_ih = (const float*)d_in[3];   // [1024]
  const float* b_hh = (const float*)d_in[4];   // [1024]
  const float* W_fc = (const float*)d_in[5];   // [256,256]
  const float* b_fc = (const float*)d_in[6];   // [256]
  float* out = (float*)d_out;                  // [2048,256]

  short* wpack = (short*)d_ws;                 // 9*64*512 shorts = 576 KB
  short* wfcp  = wpack + 9 * 64 * 512;         // 8*16*512 shorts = 128 KB

  hipLaunchKernelGGL(pack_w, dim3(144), dim3(256), 0, stream, W_hh, W_ih, wpack);
  hipLaunchKernelGGL(pack_wfc, dim3(32), dim3(256), 0, stream, W_fc, wfcp);
  hipLaunchKernelGGL(lstm_main, dim3(64), dim3(512), 0, stream, obs,
                     (const short8*)wpack, (const short8*)wfcp,
                     b_ih, b_hh, b_fc, out);
}